// Round 1
// baseline (286.602 us; speedup 1.0000x reference)
//
#include <hip/hip_runtime.h>
#include <cstddef>

#define BB 4
#define HH 8
#define SS 2048
#define DD 8
#define SCALE 0.35355339059327378f  // 1/sqrt(8)

// ---------------- Kernel 1: fused q/k projection + KX packing ----------------
// One thread per (b,h,s) row. Writes:
//   Q[row*8 + d]   (fp32, 2 MB)
//   KX[row*16 + {0..7:k, 8..15:x}]  (fp32, 4 MB)
__global__ __launch_bounds__(256) void proj_kernel(
    const float* __restrict__ x, const float* __restrict__ Wq,
    const float* __restrict__ bq, const float* __restrict__ Wk,
    const float* __restrict__ bk, float* __restrict__ Q,
    float* __restrict__ KX) {
  const int t = blockIdx.x * 256 + threadIdx.x;  // 0 .. B*H*S-1
  const float4 x0 = ((const float4*)(x + (size_t)t * 8))[0];
  const float4 x1 = ((const float4*)(x + (size_t)t * 8))[1];
  const float xr[8] = {x0.x, x0.y, x0.z, x0.w, x1.x, x1.y, x1.z, x1.w};
  float q[8], k[8];
#pragma unroll
  for (int i = 0; i < 8; ++i) {
    float aq = bq[i], ak = bk[i];
#pragma unroll
    for (int j = 0; j < 8; ++j) {
      aq = fmaf(xr[j], Wq[i * 8 + j], aq);
      ak = fmaf(xr[j], Wk[i * 8 + j], ak);
    }
    q[i] = aq;
    k[i] = ak;
  }
  float4* qp = (float4*)(Q + (size_t)t * 8);
  qp[0] = make_float4(q[0], q[1], q[2], q[3]);
  qp[1] = make_float4(q[4], q[5], q[6], q[7]);
  float4* kp = (float4*)(KX + (size_t)t * 16);
  kp[0] = make_float4(k[0], k[1], k[2], k[3]);
  kp[1] = make_float4(k[4], k[5], k[6], k[7]);
  kp[2] = x0;
  kp[3] = x1;
}

// ---------------- Kernel 2: flash-style attention ----------------
// grid (64, 32): blockIdx.y = bh, blockIdx.x = 32-row q chunk.
// 256 threads = 4 waves; each wave owns 8 q rows, lanes sweep j.
// LDS: 1024 key rows staged at a time (2 chunks), 16 floats/row (k|x),
// XOR-rotated float4 groups to kill ds_read_b128 bank conflicts.
__global__ __launch_bounds__(256, 2) void attn_kernel(
    const float* __restrict__ mask, const float* __restrict__ Q,
    const float* __restrict__ KX, float* __restrict__ out) {
  __shared__ float4 ldsv[4096];  // 64 KB
  const int bh = blockIdx.y;
  const int b = bh >> 3;
  const int tid = threadIdx.x;
  const int wave = tid >> 6, lane = tid & 63;
  const int rowBase = blockIdx.x * 32 + wave * 8;

  // q fragments for this wave's 8 rows (wave-uniform addresses -> broadcast)
  float4 qv[8][2];
#pragma unroll
  for (int r = 0; r < 8; ++r) {
    const float4* qp = (const float4*)(Q + ((size_t)bh * SS + rowBase + r) * 8);
    qv[r][0] = qp[0];
    qv[r][1] = qp[1];
  }
  float m[8], l[8], o[8][8];
#pragma unroll
  for (int r = 0; r < 8; ++r) {
    m[r] = -1e30f;
    l[r] = 0.0f;
#pragma unroll
    for (int d = 0; d < 8; ++d) o[r][d] = 0.0f;
  }

  const float* mrow = mask + (size_t)b * SS * SS + (size_t)rowBase * SS;

  for (int chunk = 0; chunk < 2; ++chunk) {
    __syncthreads();
    // stage 1024 rows of KX -> LDS with swizzle: phys = (f4 & ~3) | ((g + (j>>1)) & 3)
    const float4* src = (const float4*)(KX + ((size_t)bh * SS + chunk * 1024) * 16);
#pragma unroll
    for (int i = 0; i < 16; ++i) {
      const int f4 = tid + i * 256;  // 0..4095
      const int pg = ((f4 & 3) + (f4 >> 3)) & 3;
      ldsv[(f4 & ~3) | pg] = src[f4];
    }
    __syncthreads();
    const int jbase = chunk * 1024;

    // prefetch jb=0
    float mskc[8];
    float4 kxc[4];
    {
      const int j = lane;
#pragma unroll
      for (int r = 0; r < 8; ++r) mskc[r] = mrow[(size_t)r * SS + jbase + j];
      const float4* row = ldsv + j * 4;
      const int rot = (j >> 1) & 3;
#pragma unroll
      for (int g = 0; g < 4; ++g) kxc[g] = row[(g + rot) & 3];
    }

    for (int jb = 0; jb < 16; ++jb) {
      // one-deep software pipeline: prefetch jb+1 (wraps to jb0, harmless)
      float mskn[8];
      float4 kxn[4];
      {
        const int jn = (((jb + 1) & 15) * 64) + lane;
        const float4* row = ldsv + jn * 4;
        const int rot = (jn >> 1) & 3;
#pragma unroll
        for (int g = 0; g < 4; ++g) kxn[g] = row[(g + rot) & 3];
#pragma unroll
        for (int r = 0; r < 8; ++r) mskn[r] = mrow[(size_t)r * SS + jbase + jn];
      }
      const float4 k0 = kxc[0], k1 = kxc[1], xr0 = kxc[2], xr1 = kxc[3];
#pragma unroll
      for (int r = 0; r < 8; ++r) {
        float dot = qv[r][0].x * k0.x;
        dot = fmaf(qv[r][0].y, k0.y, dot);
        dot = fmaf(qv[r][0].z, k0.z, dot);
        dot = fmaf(qv[r][0].w, k0.w, dot);
        dot = fmaf(qv[r][1].x, k1.x, dot);
        dot = fmaf(qv[r][1].y, k1.y, dot);
        dot = fmaf(qv[r][1].z, k1.z, dot);
        dot = fmaf(qv[r][1].w, k1.w, dot);
        const float s = fmaf(mskc[r], -10000.0f, dot * SCALE);
        if (s <= m[r]) {  // hot path: no rescale
          const float p = __expf(s - m[r]);
          l[r] += p;
          o[r][0] = fmaf(p, xr0.x, o[r][0]);
          o[r][1] = fmaf(p, xr0.y, o[r][1]);
          o[r][2] = fmaf(p, xr0.z, o[r][2]);
          o[r][3] = fmaf(p, xr0.w, o[r][3]);
          o[r][4] = fmaf(p, xr1.x, o[r][4]);
          o[r][5] = fmaf(p, xr1.y, o[r][5]);
          o[r][6] = fmaf(p, xr1.z, o[r][6]);
          o[r][7] = fmaf(p, xr1.w, o[r][7]);
        } else {  // rare: new max, rescale (p == 1)
          const float a = __expf(m[r] - s);
          l[r] = fmaf(l[r], a, 1.0f);
          o[r][0] = fmaf(o[r][0], a, xr0.x);
          o[r][1] = fmaf(o[r][1], a, xr0.y);
          o[r][2] = fmaf(o[r][2], a, xr0.z);
          o[r][3] = fmaf(o[r][3], a, xr0.w);
          o[r][4] = fmaf(o[r][4], a, xr1.x);
          o[r][5] = fmaf(o[r][5], a, xr1.y);
          o[r][6] = fmaf(o[r][6], a, xr1.z);
          o[r][7] = fmaf(o[r][7], a, xr1.w);
          m[r] = s;
        }
      }
#pragma unroll
      for (int g = 0; g < 4; ++g) kxc[g] = kxn[g];
#pragma unroll
      for (int r = 0; r < 8; ++r) mskc[r] = mskn[r];
    }
  }

  // cross-lane merge of online-softmax partials (butterfly over 64 lanes)
#pragma unroll
  for (int r = 0; r < 8; ++r) {
    float mr = m[r];
#pragma unroll
    for (int off = 32; off; off >>= 1) mr = fmaxf(mr, __shfl_xor(mr, off));
    const float a = __expf(m[r] - mr);
    float lr = l[r] * a;
    float od[8];
#pragma unroll
    for (int d = 0; d < 8; ++d) od[d] = o[r][d] * a;
#pragma unroll
    for (int off = 32; off; off >>= 1) {
      lr += __shfl_xor(lr, off);
#pragma unroll
      for (int d = 0; d < 8; ++d) od[d] += __shfl_xor(od[d], off);
    }
    if (lane == 0) {
      const float inv = 1.0f / lr;
      float4* op = (float4*)(out + ((size_t)bh * SS + rowBase + r) * 8);
      op[0] = make_float4(od[0] * inv, od[1] * inv, od[2] * inv, od[3] * inv);
      op[1] = make_float4(od[4] * inv, od[5] * inv, od[6] * inv, od[7] * inv);
    }
  }
}

extern "C" void kernel_launch(void* const* d_in, const int* in_sizes, int n_in,
                              void* d_out, int out_size, void* d_ws, size_t ws_size,
                              hipStream_t stream) {
  (void)in_sizes;
  (void)n_in;
  (void)out_size;
  (void)ws_size;
  const float* x = (const float*)d_in[0];
  const float* mask = (const float*)d_in[1];
  const float* Wq = (const float*)d_in[2];
  const float* bq = (const float*)d_in[3];
  const float* Wk = (const float*)d_in[4];
  const float* bk = (const float*)d_in[5];
  float* Q = (float*)d_ws;                      // B*H*S*8 floats = 2 MB
  float* KX = Q + (size_t)BB * HH * SS * DD;    // B*H*S*16 floats = 4 MB
  float* out = (float*)d_out;

  proj_kernel<<<dim3((BB * HH * SS) / 256), dim3(256), 0, stream>>>(
      x, Wq, bq, Wk, bk, Q, KX);
  attn_kernel<<<dim3(SS / 32, BB * HH), dim3(256), 0, stream>>>(mask, Q, KX, out);
}

// Round 2
// 170.074 us; speedup vs baseline: 1.6852x; 1.6852x over previous
//
#include <hip/hip_runtime.h>
#include <cstddef>

#define BB 4
#define HH 8
#define SS 2048
// Q pre-scale: (1/sqrt(8)) * log2(e)  -> scores come out of MFMA already in exp2 space
#define QSC 0.5101336573f
// mask pre-scale: -10000 * log2(e)
#define MSC (-14426.950408889634f)

typedef __attribute__((ext_vector_type(4))) float v4f;
typedef __attribute__((ext_vector_type(8))) _Float16 v8h;
typedef __attribute__((ext_vector_type(4))) _Float16 v4h;

// ---------------- Kernel 1: q/k projection (f16) + x transpose (f16) ----------------
// One thread per (bh,s) row. Grid: 256 blocks x 256 thr; block = 256 consecutive s of one bh.
// Writes: Qh[bh][s][8] f16 (q pre-scaled by QSC), Kh[bh][s][8] f16, XT[bh][d][s] f16.
__global__ __launch_bounds__(256) void proj_kernel(
    const float* __restrict__ x, const float* __restrict__ Wq,
    const float* __restrict__ bq, const float* __restrict__ Wk,
    const float* __restrict__ bk, _Float16* __restrict__ Qh,
    _Float16* __restrict__ Kh, _Float16* __restrict__ XT) {
  __shared__ _Float16 xt[8 * 264];  // [d][s-in-block], pitch 264 keeps b128 reads aligned
  const int tid = threadIdx.x;
  const int t = blockIdx.x * 256 + tid;     // global row
  const int bh = blockIdx.x >> 3;           // 8 blocks per bh
  const int sb = (blockIdx.x & 7) * 256;
  const float4 x0 = ((const float4*)(x + (size_t)t * 8))[0];
  const float4 x1 = ((const float4*)(x + (size_t)t * 8))[1];
  const float xr[8] = {x0.x, x0.y, x0.z, x0.w, x1.x, x1.y, x1.z, x1.w};
  v8h qv, kv;
#pragma unroll
  for (int i = 0; i < 8; ++i) {
    float aq = bq[i], ak = bk[i];
#pragma unroll
    for (int j = 0; j < 8; ++j) {
      aq = fmaf(xr[j], Wq[i * 8 + j], aq);
      ak = fmaf(xr[j], Wk[i * 8 + j], ak);
    }
    qv[i] = (_Float16)(aq * QSC);
    kv[i] = (_Float16)ak;
  }
  *(v8h*)(Qh + (size_t)t * 8) = qv;
  *(v8h*)(Kh + (size_t)t * 8) = kv;
#pragma unroll
  for (int d = 0; d < 8; ++d) xt[d * 264 + tid] = (_Float16)xr[d];
  __syncthreads();
  const int d = tid >> 5, k8 = (tid & 31) * 8;
  *(v8h*)(XT + ((size_t)bh * 8 + d) * SS + sb + k8) =
      *(const v8h*)(xt + d * 264 + k8);
}

// ---------------- Kernel 2: MFMA flash attention ----------------
// grid (128, 4): blockIdx.y = b, blockIdx.x = 16-row q tile. 512 thr = 8 waves;
// wave w = head w (all waves share the SAME q rows -> ONE mask tile serves all 8 heads).
// Mask tile (16q x 64keys fp32) is transposed+scaled(-1e4*log2e) into LDS during staging,
// double-buffered, one barrier per chunk.
// QK^T as S^T via mfma_f32_16x16x32_f16 (A=K rows, B=Q^T; quads 1-3 of A are garbage,
// killed by explicit zeros in B). S^T C-layout == PV A-operand layout of 16x16x16f16.
__global__ __launch_bounds__(512, 4) void attn_kernel(
    const float* __restrict__ mask, const _Float16* __restrict__ Qh,
    const _Float16* __restrict__ Kh, const _Float16* __restrict__ XT,
    float* __restrict__ out) {
  __shared__ float mlds[2][64 * 17];  // [key][q], pitch 17 breaks bank aliasing
  const int b = blockIdx.y;
  const int qb = blockIdx.x * 16;
  const int tid = threadIdx.x;
  const int wave = tid >> 6, lane = tid & 63;
  const int bh = b * HH + wave;
  const int quad = lane >> 4, q15 = lane & 15;
  const float* msrc = mask + ((size_t)b * SS + qb) * SS;
  const int sr = tid >> 5;        // staging: q row 0..15
  const int sc = (tid & 31) * 2;  // staging: key pair

  {  // stage chunk 0
    const float2 mv = *(const float2*)(msrc + (size_t)sr * SS + sc);
    mlds[0][(sc + 0) * 17 + sr] = mv.x * MSC;
    mlds[0][(sc + 1) * 17 + sr] = mv.y * MSC;
  }

  v8h qfrag;
  {  // B-operand: Q[q=lane&15][k], real only in quad 0 (k=0..7), zeros elsewhere
    const v8h ql = *(const v8h*)(Qh + ((size_t)bh * SS + qb + q15) * 8);
#pragma unroll
    for (int i = 0; i < 8; ++i) qfrag[i] = (quad == 0) ? ql[i] : (_Float16)0;
  }

  float m = -3.0e38f, l = 0.0f;
  v4f o = {0.f, 0.f, 0.f, 0.f};
  __syncthreads();

  for (int ch = 0; ch < SS / 64; ++ch) {
    const float* cur = mlds[ch & 1];
    if (ch < SS / 64 - 1) {  // prefetch next mask tile into other buffer
      float* nxt = mlds[(ch + 1) & 1];
      const float2 mv =
          *(const float2*)(msrc + (size_t)sr * SS + (ch + 1) * 64 + sc);
      nxt[(sc + 0) * 17 + sr] = mv.x * MSC;
      nxt[(sc + 1) * 17 + sr] = mv.y * MSC;
    }
    const int kb = ch * 64;
    const _Float16* krow = Kh + ((size_t)bh * SS + kb + q15) * 8;
    const v4f zero = {0.f, 0.f, 0.f, 0.f};
    v4f c[4];
#pragma unroll
    for (int t = 0; t < 4; ++t)
      c[t] = __builtin_amdgcn_mfma_f32_16x16x32_f16(
          *(const v8h*)(krow + t * 128), qfrag, zero, 0, 0, 0);

    // scores (exp2 space): s = qk*scale*log2e + mask*(-1e4*log2e)
    float s[16];
    float mx = m;
#pragma unroll
    for (int t = 0; t < 4; ++t)
#pragma unroll
      for (int r = 0; r < 4; ++r) {
        s[t * 4 + r] = c[t][r] + cur[(t * 16 + quad * 4 + r) * 17 + q15];
        mx = fmaxf(mx, s[t * 4 + r]);
      }
    mx = fmaxf(mx, __shfl_xor(mx, 16));
    mx = fmaxf(mx, __shfl_xor(mx, 32));
    const float alpha = __builtin_amdgcn_exp2f(m - mx);
    m = mx;
    float ls = 0.0f;
    v4h pa[4];
#pragma unroll
    for (int t = 0; t < 4; ++t)
#pragma unroll
      for (int r = 0; r < 4; ++r) {
        const float p = __builtin_amdgcn_exp2f(s[t * 4 + r] - mx);
        ls += p;
        pa[t][r] = (_Float16)p;
      }
    l = l * alpha + ls;
    // O rows are q=quad*4+r; alpha lives at lane q (quad 0 copy) -> 4 shuffles
    const float a0 = __shfl(alpha, quad * 4 + 0);
    const float a1 = __shfl(alpha, quad * 4 + 1);
    const float a2 = __shfl(alpha, quad * 4 + 2);
    const float a3 = __shfl(alpha, quad * 4 + 3);
    o[0] *= a0;
    o[1] *= a1;
    o[2] *= a2;
    o[3] *= a3;
    // PV: A=P (S^T C-frag IS the A-layout), B=X^T rows (d=lane&7 dup to lanes 8-15)
    const _Float16* xrow =
        XT + ((size_t)bh * 8 + (q15 & 7)) * SS + kb + quad * 4;
#pragma unroll
    for (int t = 0; t < 4; ++t)
      o = __builtin_amdgcn_mfma_f32_16x16x16f16(
          pa[t], *(const v4h*)(xrow + t * 16), o, 0, 0, 0);
    __syncthreads();
  }

  // epilogue: reduce l across quads (same q), normalize, write
  l += __shfl_xor(l, 16);
  l += __shfl_xor(l, 32);
  const float inv = 1.0f / l;
  const float i0 = __shfl(inv, quad * 4 + 0);
  const float i1 = __shfl(inv, quad * 4 + 1);
  const float i2 = __shfl(inv, quad * 4 + 2);
  const float i3 = __shfl(inv, quad * 4 + 3);
  if (q15 < 8) {
    float* obase = out + ((size_t)bh * SS + qb + quad * 4) * 8 + q15;
    obase[0] = o[0] * i0;
    obase[8] = o[1] * i1;
    obase[16] = o[2] * i2;
    obase[24] = o[3] * i3;
  }
}

extern "C" void kernel_launch(void* const* d_in, const int* in_sizes, int n_in,
                              void* d_out, int out_size, void* d_ws, size_t ws_size,
                              hipStream_t stream) {
  (void)in_sizes;
  (void)n_in;
  (void)out_size;
  (void)ws_size;
  const float* x = (const float*)d_in[0];
  const float* mask = (const float*)d_in[1];
  const float* Wq = (const float*)d_in[2];
  const float* bq = (const float*)d_in[3];
  const float* Wk = (const float*)d_in[4];
  const float* bk = (const float*)d_in[5];
  _Float16* Qh = (_Float16*)d_ws;                      // 1 MB
  _Float16* Kh = Qh + (size_t)BB * HH * SS * 8;        // 1 MB
  _Float16* XT = Kh + (size_t)BB * HH * SS * 8;        // 1 MB
  float* out = (float*)d_out;

  proj_kernel<<<dim3(BB * HH * SS / 256), dim3(256), 0, stream>>>(
      x, Wq, bq, Wk, bk, Qh, Kh, XT);
  attn_kernel<<<dim3(SS / 16, BB), dim3(512), 0, stream>>>(
      mask, Qh, Kh, XT, out);
}